// Round 12
// baseline (241.920 us; speedup 1.0000x reference)
//
#include <hip/hip_runtime.h>
#include <hip/hip_bf16.h>

// MultiHeadAttnBlock — R12 DIAGNOSTIC build (output identical to R11).
// attn_pv repeats its k-loop rep=8x, colstats rep=20x (acc re-zeroed per rep),
// pushing both above the 40us profiler cutoff to expose per-body duration and
// counters. dur_us will read ~150us by design; decomposition:
//   body_attn = dur(attn_pv)/8, body_colstats = dur(colstats)/20,
//   gaps = 51.7 - bodies  ->  decides body-bound vs launch-bound.

#define HWSZ 4096
#define QSCALE2 0.12752649759422368f  // 128^-0.5 * log2(e)
#define QSPLIT 16                     // colstats query-axis split
#define KSPLIT 8                      // attn_pv key-axis split
#define EPS 1e-6f

typedef __bf16 bf16x8 __attribute__((ext_vector_type(8)));
typedef float f32x4 __attribute__((ext_vector_type(4)));

union FragU { uint4 u; bf16x8 v; };

#if __has_builtin(__builtin_amdgcn_exp2f)
#define EXP2F(x) __builtin_amdgcn_exp2f(x)
#else
#define EXP2F(x) exp2f(x)
#endif

// pack two f32 -> two bf16 (round-half via +0x8000, then v_perm byte select)
__device__ __forceinline__ unsigned int pack_bf16(float lo, float hi) {
  unsigned int ul, uh;
  __builtin_memcpy(&ul, &lo, 4);
  __builtin_memcpy(&uh, &hi, 4);
  return __builtin_amdgcn_perm(uh + 0x8000u, ul + 0x8000u, 0x07060302u);
}

// single-instruction packed f32->bf16 (RNE), gfx950
__device__ __forceinline__ unsigned int cvt_pk_bf16(float lo, float hi) {
  unsigned int r;
  asm("v_cvt_pk_bf16_f32 %0, %1, %2" : "=v"(r) : "v"(lo), "v"(hi));
  return r;
}

// ---------------- K1: prep — weight cvt to bf16 + per-channel GN partials ---
__global__ __launch_bounds__(256) void prep_kernel(
    const float* __restrict__ wq, const float* __restrict__ wk,
    const float* __restrict__ wv, const float* __restrict__ wp,
    const float* __restrict__ x, __hip_bfloat16* __restrict__ wb,
    float* __restrict__ gnpart) {
  int b = blockIdx.x, t = threadIdx.x;
  if (b < 64) {
    int m = b >> 4, chunk = b & 15;
    const float* src = (m == 0) ? wq : (m == 1) ? wk : (m == 2) ? wv : wp;
    float sc = (m == 0) ? QSCALE2 : 1.0f;
    int idx = chunk * 1024 + t * 4;
    float4 v = *reinterpret_cast<const float4*>(src + idx);
    uint2 st;
    st.x = pack_bf16(v.x * sc, v.y * sc);
    st.y = pack_bf16(v.z * sc, v.w * sc);
    *reinterpret_cast<uint2*>(wb + m * 16384 + idx) = st;
  } else {
    int ch = b - 64;
    const float4* x4 = reinterpret_cast<const float4*>(x + ch * HWSZ);
    float s = 0.f, ss = 0.f;
    for (int e = t; e < 1024; e += 256) {
      float4 v = x4[e];
      s += v.x + v.y + v.z + v.w;
      ss += v.x * v.x + v.y * v.y + v.z * v.z + v.w * v.w;
    }
    for (int off = 32; off; off >>= 1) {
      s += __shfl_down(s, off);
      ss += __shfl_down(ss, off);
    }
    __shared__ float rs[4], rss[4];
    int wid = t >> 6;
    if ((t & 63) == 0) { rs[wid] = s; rss[wid] = ss; }
    __syncthreads();
    if (t == 0) {
      gnpart[ch] = rs[0] + rs[1] + rs[2] + rs[3];
      gnpart[128 + ch] = rss[0] + rss[1] + rss[2] + rss[3];
    }
  }
}

// ---------------- K2: GN-apply + QKV as MFMA GEMM (512 thr, coalesced epi) --
__global__ __launch_bounds__(512) void qkv_mfma_kernel(
    const float* __restrict__ x, const float* __restrict__ gnpart,
    const float* __restrict__ gamma, const float* __restrict__ beta,
    const __hip_bfloat16* __restrict__ wb, const float* __restrict__ bq,
    const float* __restrict__ bk, const float* __restrict__ bv,
    __hip_bfloat16* __restrict__ qt, __hip_bfloat16* __restrict__ kt,
    __hip_bfloat16* __restrict__ vb) {
  __shared__ float stats_lds[32][2];
  __shared__ __align__(16) __hip_bfloat16 xnT[16][136];
  __shared__ __align__(16) __hip_bfloat16 qs_[4][16][40];
  __shared__ __align__(16) __hip_bfloat16 ks_[4][16][40];
  __shared__ __align__(16) __hip_bfloat16 vs_[128][24];
  int t = threadIdx.x;
  int p0 = blockIdx.x * 16;
  if (t < 32) {
    float s = 0.f, ss = 0.f;
#pragma unroll
    for (int q = 0; q < 4; ++q) {
      s += gnpart[t * 4 + q];
      ss += gnpart[128 + t * 4 + q];
    }
    float mu = s * (1.f / 16384.f);
    float var = ss * (1.f / 16384.f) - mu * mu;
    stats_lds[t][0] = mu;
    stats_lds[t][1] = rsqrtf(var + EPS);
  }
  __syncthreads();
#pragma unroll
  for (int e = t; e < 2048; e += 512) {
    int c = e >> 4, p = e & 15;
    int g = c >> 2;
    float xv = x[c * HWSZ + p0 + p];
    float xn = (xv - stats_lds[g][0]) * stats_lds[g][1] * gamma[c] + beta[c];
    xnT[p][c] = __float2bfloat16(xn);
  }
  __syncthreads();
  int lane = t & 63, w = t >> 6;
  int l15 = lane & 15, g = lane >> 4;
  FragU bfr[4];
#pragma unroll
  for (int kk = 0; kk < 4; ++kk)
    bfr[kk].u = *reinterpret_cast<const uint4*>(&xnT[l15][kk * 32 + 8 * g]);
  int o0 = w * 16;
#define DO_CONV(WMAT, BIAS, BSCALE, LDSW)                                        \
  {                                                                              \
    f32x4 bi = *reinterpret_cast<const f32x4*>((BIAS) + o0 + 4 * g);             \
    f32x4 acc = bi * (BSCALE);                                                   \
    _Pragma("unroll") for (int kk = 0; kk < 4; ++kk) {                           \
      FragU a;                                                                   \
      a.u = *reinterpret_cast<const uint4*>((WMAT) +                             \
            (o0 + l15) * 128 + kk * 32 + 8 * g);                                 \
      acc = __builtin_amdgcn_mfma_f32_16x16x32_bf16(a.v, bfr[kk].v, acc, 0, 0, 0); \
    }                                                                            \
    _Pragma("unroll") for (int r = 0; r < 4; ++r) {                              \
      int o = o0 + 4 * g + r;                                                    \
      LDSW;                                                                      \
    }                                                                            \
  }
  DO_CONV(wb, bq, QSCALE2, qs_[o & 3][l15][o >> 2] = __float2bfloat16(acc[r]))
  DO_CONV(wb + 16384, bk, 1.0f, ks_[o & 3][l15][o >> 2] = __float2bfloat16(acc[r]))
  DO_CONV(wb + 32768, bv, 1.0f, vs_[o][l15] = __float2bfloat16(acc[r]))
#undef DO_CONV
  __syncthreads();
  if (t < 256) {
    int row = t >> 2, ch = t & 3;
    int h = row >> 4, p = row & 15;
    uint4 vq = *reinterpret_cast<const uint4*>(&qs_[h][p][ch * 8]);
    *reinterpret_cast<uint4*>(qt + (h * HWSZ + p0 + p) * 32 + ch * 8) = vq;
  } else {
    int tt = t - 256;
    int row = tt >> 2, ch = tt & 3;
    int h = row >> 4, p = row & 15;
    uint4 vk = *reinterpret_cast<const uint4*>(&ks_[h][p][ch * 8]);
    *reinterpret_cast<uint4*>(kt + (h * HWSZ + p0 + p) * 32 + ch * 8) = vk;
  }
  if (t < 256) {
    int o = t >> 1, half = t & 1;
    uint4 vv = *reinterpret_cast<const uint4*>(&vs_[o][half * 8]);
    *reinterpret_cast<uint4*>(vb + o * HWSZ + p0 + half * 8) = vv;
  }
}

// ---------------- K3: colstats (DIAG: rep x20) -------------------------------
__global__ __launch_bounds__(256, 4) void colstats_kernel(
    const __hip_bfloat16* __restrict__ qt, const __hip_bfloat16* __restrict__ kt,
    float* __restrict__ colpart, int rep) {
  int h = blockIdx.y, t = threadIdx.x, qs = blockIdx.z;
  int w = t >> 6, lane = t & 63;
  int l15 = lane & 15, g = lane >> 4;
  int k0 = blockIdx.x * 256 + w * 64;
  FragU a[4];
#pragma unroll
  for (int u = 0; u < 4; ++u)
    a[u].u = *reinterpret_cast<const uint4*>(kt + (h * HWSZ + k0 + u * 16 + l15) * 32 + 8 * g);
  const __hip_bfloat16* qbase =
      qt + h * HWSZ * 32 + (qs * (HWSZ / QSPLIT) + l15) * 32 + 8 * g;
  f32x4 z = {0.f, 0.f, 0.f, 0.f};
  float l[4][4];
  for (int rp = 0; rp < rep; ++rp) {
#pragma unroll
    for (int u = 0; u < 4; ++u)
#pragma unroll
      for (int r = 0; r < 4; ++r) l[u][r] = 0.f;
#pragma unroll 2
    for (int it = 0; it < HWSZ / QSPLIT / 16; ++it) {
      FragU b;
      b.u = *reinterpret_cast<const uint4*>(qbase + it * 512);
#pragma unroll
      for (int u = 0; u < 4; ++u) {
        f32x4 d = __builtin_amdgcn_mfma_f32_16x16x32_bf16(a[u].v, b.v, z, 0, 0, 0);
#pragma unroll
        for (int r = 0; r < 4; ++r) l[u][r] += EXP2F(d[r]);
      }
    }
  }
#pragma unroll
  for (int off = 1; off < 16; off <<= 1)
#pragma unroll
    for (int u = 0; u < 4; ++u)
#pragma unroll
      for (int r = 0; r < 4; ++r) l[u][r] += __shfl_xor(l[u][r], off);
  if (l15 == 0) {
#pragma unroll
    for (int u = 0; u < 4; ++u)
#pragma unroll
      for (int r = 0; r < 4; ++r)
        colpart[(qs * 4 + h) * HWSZ + k0 + u * 16 + 4 * g + r] = l[u][r];
  }
}

// ---------------- K4: attn_pv (DIAG: rep x8) ---------------------------------
__global__ __launch_bounds__(256, 2) void attn_pv_kernel(
    const __hip_bfloat16* __restrict__ qt, const __hip_bfloat16* __restrict__ kt,
    const __hip_bfloat16* __restrict__ vb, const float* __restrict__ colpart,
    __hip_bfloat16* __restrict__ aopb, int rep) {
  __shared__ __align__(16) char p_lds[4][4][2048];
  __shared__ float c2_lds[HWSZ / KSPLIT];
  int h = blockIdx.y, t = threadIdx.x;
  int kc0 = blockIdx.z * (HWSZ / KSPLIT);
#pragma unroll
  for (int e = t; e < HWSZ / KSPLIT; e += 256) {
    float s = 0.f;
#pragma unroll
    for (int qs = 0; qs < QSPLIT; ++qs) s += colpart[(qs * 4 + h) * HWSZ + kc0 + e];
    c2_lds[e] = -__log2f(s);
  }
  __syncthreads();
  int w = t >> 6, lane = t & 63;
  int l15 = lane & 15, g = lane >> 4;
  int swz = l15 & 7;
  int i0 = blockIdx.x * 256 + w * 64;
  FragU bq[4];
#pragma unroll
  for (int qs = 0; qs < 4; ++qs)
    bq[qs].u = *reinterpret_cast<const uint4*>(
        qt + (h * HWSZ + i0 + qs * 16 + l15) * 32 + 8 * g);
  f32x4 acc[4][2];
  __hip_bfloat16* ao = aopb + blockIdx.z * (128 * HWSZ);
  for (int rp = 0; rp < rep; ++rp) {
#pragma unroll
    for (int qs = 0; qs < 4; ++qs)
#pragma unroll
      for (int ch = 0; ch < 2; ++ch) acc[qs][ch] = (f32x4){0.f, 0.f, 0.f, 0.f};
    for (int k0 = kc0; k0 < kc0 + HWSZ / KSPLIT; k0 += 64) {
      FragU a[4];
      f32x4 c2[4];
#pragma unroll
      for (int kt4 = 0; kt4 < 4; ++kt4) {
        a[kt4].u = *reinterpret_cast<const uint4*>(
            kt + (h * HWSZ + k0 + kt4 * 16 + l15) * 32 + 8 * g);
        c2[kt4] = *reinterpret_cast<const f32x4*>(c2_lds + (k0 - kc0) + kt4 * 16 + 4 * g);
      }
      FragU bvf[2][2];
#pragma unroll
      for (int ks = 0; ks < 2; ++ks)
#pragma unroll
        for (int ch = 0; ch < 2; ++ch)
          bvf[ks][ch].u = *reinterpret_cast<const uint4*>(
              vb + ((l15 + 16 * ch) * 4 + h) * HWSZ + k0 + ks * 32 + 8 * g);
#pragma unroll
      for (int qs = 0; qs < 4; ++qs) {
        f32x4 st[4];
#pragma unroll
        for (int kt4 = 0; kt4 < 4; ++kt4)
          st[kt4] = __builtin_amdgcn_mfma_f32_16x16x32_bf16(a[kt4].v, bq[qs].v,
                                                            c2[kt4], 0, 0, 0);
        char* pw = p_lds[w][qs];
#pragma unroll
        for (int kt4 = 0; kt4 < 4; ++kt4) {
          uint2 pk;
          pk.x = cvt_pk_bf16(EXP2F(st[kt4][0]), EXP2F(st[kt4][1]));
          pk.y = cvt_pk_bf16(EXP2F(st[kt4][2]), EXP2F(st[kt4][3]));
          int c8 = kt4 * 4 + g;
          int byte_w = l15 * 128 + ((((c8 >> 1) ^ swz)) << 4) + ((c8 & 1) << 3);
          *reinterpret_cast<uint2*>(pw + byte_w) = pk;
        }
#pragma unroll
        for (int ks = 0; ks < 2; ++ks) {
          FragU ap;
          int byte_r = l15 * 128 + (((ks * 4 + g) ^ swz) << 4);
          ap.u = *reinterpret_cast<const uint4*>(pw + byte_r);
#pragma unroll
          for (int ch = 0; ch < 2; ++ch)
            acc[qs][ch] = __builtin_amdgcn_mfma_f32_16x16x32_bf16(
                ap.v, bvf[ks][ch].v, acc[qs][ch], 0, 0, 0);
        }
      }
    }
  }
#pragma unroll
  for (int qs = 0; qs < 4; ++qs)
#pragma unroll
    for (int ch = 0; ch < 2; ++ch) {
      uint2 pk;
      pk.x = cvt_pk_bf16(acc[qs][ch][0], acc[qs][ch][1]);
      pk.y = cvt_pk_bf16(acc[qs][ch][2], acc[qs][ch][3]);
      *reinterpret_cast<uint2*>(
          ao + ((l15 + 16 * ch) * 4 + h) * HWSZ + i0 + qs * 16 + 4 * g) = pk;
    }
}

// ---------------- K5: reduce bf16 split-k partials + proj via MFMA ----------
__global__ __launch_bounds__(512) void proj_mfma_kernel(
    const __hip_bfloat16* __restrict__ aopb, const __hip_bfloat16* __restrict__ wpb,
    const float* __restrict__ bp, const float* __restrict__ x,
    float* __restrict__ out) {
  __shared__ __align__(16) __hip_bfloat16 aoT[16][136];
  __shared__ __align__(16) float obuf[128][20];
  int t = threadIdx.x;
  int p0 = blockIdx.x * 16;
  if (t < 256) {
    int c = t >> 1, half = t & 1;
    float s[8];
#pragma unroll
    for (int j = 0; j < 8; ++j) s[j] = 0.f;
#pragma unroll
    for (int z = 0; z < KSPLIT; ++z) {
      FragU u;
      u.u = *reinterpret_cast<const uint4*>(aopb + z * (128 * HWSZ) + c * HWSZ + p0 + half * 8);
#pragma unroll
      for (int j = 0; j < 8; ++j) s[j] += (float)u.v[j];
    }
#pragma unroll
    for (int j = 0; j < 8; ++j) aoT[half * 8 + j][c] = __float2bfloat16(s[j]);
  }
  __syncthreads();
  int lane = t & 63, w = t >> 6;
  int l15 = lane & 15, g = lane >> 4;
  FragU bfr[4];
#pragma unroll
  for (int kk = 0; kk < 4; ++kk)
    bfr[kk].u = *reinterpret_cast<const uint4*>(&aoT[l15][kk * 32 + 8 * g]);
  int o0 = w * 16;
  f32x4 acc = *reinterpret_cast<const f32x4*>(bp + o0 + 4 * g);
#pragma unroll
  for (int kk = 0; kk < 4; ++kk) {
    FragU a;
    a.u = *reinterpret_cast<const uint4*>(wpb + (o0 + l15) * 128 + kk * 32 + 8 * g);
    acc = __builtin_amdgcn_mfma_f32_16x16x32_bf16(a.v, bfr[kk].v, acc, 0, 0, 0);
  }
#pragma unroll
  for (int r = 0; r < 4; ++r) obuf[o0 + 4 * g + r][l15] = acc[r];
  __syncthreads();
  int row = t >> 2, ch = t & 3;
  float4 o4 = *reinterpret_cast<const float4*>(&obuf[row][ch * 4]);
  float4 xv = *reinterpret_cast<const float4*>(x + row * HWSZ + p0 + ch * 4);
  float4 rr = {o4.x + xv.x, o4.y + xv.y, o4.z + xv.z, o4.w + xv.w};
  *reinterpret_cast<float4*>(out + row * HWSZ + p0 + ch * 4) = rr;
}

extern "C" void kernel_launch(void* const* d_in, const int* in_sizes, int n_in,
                              void* d_out, int out_size, void* d_ws, size_t ws_size,
                              hipStream_t stream) {
  const float* x = (const float*)d_in[0];
  const float* gamma = (const float*)d_in[1];
  const float* beta = (const float*)d_in[2];
  const float* wq = (const float*)d_in[3];
  const float* bq = (const float*)d_in[4];
  const float* wk = (const float*)d_in[5];
  const float* bk = (const float*)d_in[6];
  const float* wv = (const float*)d_in[7];
  const float* bv = (const float*)d_in[8];
  const float* wp = (const float*)d_in[9];
  const float* bp = (const float*)d_in[10];
  float* out = (float*)d_out;

  char* ws = (char*)d_ws;
  __hip_bfloat16* qt = (__hip_bfloat16*)(ws);                    // 1 MB
  __hip_bfloat16* kt = (__hip_bfloat16*)(ws + (1 << 20));        // 1 MB
  __hip_bfloat16* vb = (__hip_bfloat16*)(ws + (2 << 20));        // 1 MB
  __hip_bfloat16* aopb = (__hip_bfloat16*)(ws + (3 << 20));      // KSPLIT MB
  char* tail = ws + ((3 + KSPLIT) << 20);
  float* colpart = (float*)(tail);                               // 1 MB
  __hip_bfloat16* wb = (__hip_bfloat16*)(tail + (1 << 20));      // 128 KB (4 mats)
  float* gnpart = (float*)(tail + (1 << 20) + (128 << 10));      // 1 KB

  prep_kernel<<<192, 256, 0, stream>>>(wq, wk, wv, wp, x, wb, gnpart);
  qkv_mfma_kernel<<<256, 512, 0, stream>>>(x, gnpart, gamma, beta, wb, bq, bk, bv,
                                           qt, kt, vb);
  colstats_kernel<<<dim3(16, 4, QSPLIT), 256, 0, stream>>>(qt, kt, colpart, 20);
  attn_pv_kernel<<<dim3(16, 4, KSPLIT), 256, 0, stream>>>(qt, kt, vb, colpart, aopb, 8);
  proj_mfma_kernel<<<256, 512, 0, stream>>>(aopb, wb + 49152, bp, x, out);
}

// Round 13
// 56.127 us; speedup vs baseline: 4.3102x; 4.3102x over previous
//
#include <hip/hip_runtime.h>
#include <hip/hip_bf16.h>

// MultiHeadAttnBlock: B=1, C=128, HEADS=4 (cph=32), GROUPS=32, H=W=64 (HW=4096)
// softmax over QUERY axis => per-key-column normalizer; log2-domain softmax
// (qt & wq pre-scaled by 128^-0.5*log2e); c2=-log2(colsum) folded into the
// QK^T MFMA C-operand. 5 kernels; dep chain stats->qkv->colsum->pv->proj is
// irreducible (grid.sync ~55us, R7; per-boundary gap ~5-6us, R12 diag).
// R12 diag: colstats body 7.5us (VALU 71%, trans-bound @16 waves/CU),
// attn_pv 6.7us. R13: colstats at 32 waves/CU (QSPLIT=32, lb(256,8)) +
// key-major colpart so attn_pv's combine is coalesced f32x4.

#define HWSZ 4096
#define QSCALE2 0.12752649759422368f  // 128^-0.5 * log2(e)
#define QSPLIT 32                     // colstats query-axis split
#define KSPLIT 8                      // attn_pv key-axis split
#define EPS 1e-6f

typedef __bf16 bf16x8 __attribute__((ext_vector_type(8)));
typedef float f32x4 __attribute__((ext_vector_type(4)));

union FragU { uint4 u; bf16x8 v; };

#if __has_builtin(__builtin_amdgcn_exp2f)
#define EXP2F(x) __builtin_amdgcn_exp2f(x)
#else
#define EXP2F(x) exp2f(x)
#endif

// pack two f32 -> two bf16 (round-half via +0x8000, then v_perm byte select)
__device__ __forceinline__ unsigned int pack_bf16(float lo, float hi) {
  unsigned int ul, uh;
  __builtin_memcpy(&ul, &lo, 4);
  __builtin_memcpy(&uh, &hi, 4);
  return __builtin_amdgcn_perm(uh + 0x8000u, ul + 0x8000u, 0x07060302u);
}

// single-instruction packed f32->bf16 (RNE), gfx950
__device__ __forceinline__ unsigned int cvt_pk_bf16(float lo, float hi) {
  unsigned int r;
  asm("v_cvt_pk_bf16_f32 %0, %1, %2" : "=v"(r) : "v"(lo), "v"(hi));
  return r;
}

// ---------------- K1: prep — weight cvt to bf16 + per-channel GN partials ---
__global__ __launch_bounds__(256) void prep_kernel(
    const float* __restrict__ wq, const float* __restrict__ wk,
    const float* __restrict__ wv, const float* __restrict__ wp,
    const float* __restrict__ x, __hip_bfloat16* __restrict__ wb,
    float* __restrict__ gnpart) {
  int b = blockIdx.x, t = threadIdx.x;
  if (b < 64) {
    int m = b >> 4, chunk = b & 15;
    const float* src = (m == 0) ? wq : (m == 1) ? wk : (m == 2) ? wv : wp;
    float sc = (m == 0) ? QSCALE2 : 1.0f;
    int idx = chunk * 1024 + t * 4;
    float4 v = *reinterpret_cast<const float4*>(src + idx);
    uint2 st;
    st.x = pack_bf16(v.x * sc, v.y * sc);
    st.y = pack_bf16(v.z * sc, v.w * sc);
    *reinterpret_cast<uint2*>(wb + m * 16384 + idx) = st;
  } else {
    int ch = b - 64;
    const float4* x4 = reinterpret_cast<const float4*>(x + ch * HWSZ);
    float s = 0.f, ss = 0.f;
    for (int e = t; e < 1024; e += 256) {
      float4 v = x4[e];
      s += v.x + v.y + v.z + v.w;
      ss += v.x * v.x + v.y * v.y + v.z * v.z + v.w * v.w;
    }
    for (int off = 32; off; off >>= 1) {
      s += __shfl_down(s, off);
      ss += __shfl_down(ss, off);
    }
    __shared__ float rs[4], rss[4];
    int wid = t >> 6;
    if ((t & 63) == 0) { rs[wid] = s; rss[wid] = ss; }
    __syncthreads();
    if (t == 0) {
      gnpart[ch] = rs[0] + rs[1] + rs[2] + rs[3];
      gnpart[128 + ch] = rss[0] + rss[1] + rss[2] + rss[3];
    }
  }
}

// ---------------- K2: GN-apply + QKV as MFMA GEMM (512 thr, coalesced epi) --
__global__ __launch_bounds__(512) void qkv_mfma_kernel(
    const float* __restrict__ x, const float* __restrict__ gnpart,
    const float* __restrict__ gamma, const float* __restrict__ beta,
    const __hip_bfloat16* __restrict__ wb, const float* __restrict__ bq,
    const float* __restrict__ bk, const float* __restrict__ bv,
    __hip_bfloat16* __restrict__ qt, __hip_bfloat16* __restrict__ kt,
    __hip_bfloat16* __restrict__ vb) {
  __shared__ float stats_lds[32][2];
  __shared__ __align__(16) __hip_bfloat16 xnT[16][136];
  __shared__ __align__(16) __hip_bfloat16 qs_[4][16][40];
  __shared__ __align__(16) __hip_bfloat16 ks_[4][16][40];
  __shared__ __align__(16) __hip_bfloat16 vs_[128][24];
  int t = threadIdx.x;
  int p0 = blockIdx.x * 16;
  if (t < 32) {
    float s = 0.f, ss = 0.f;
#pragma unroll
    for (int q = 0; q < 4; ++q) {
      s += gnpart[t * 4 + q];
      ss += gnpart[128 + t * 4 + q];
    }
    float mu = s * (1.f / 16384.f);
    float var = ss * (1.f / 16384.f) - mu * mu;
    stats_lds[t][0] = mu;
    stats_lds[t][1] = rsqrtf(var + EPS);
  }
  __syncthreads();
#pragma unroll
  for (int e = t; e < 2048; e += 512) {
    int c = e >> 4, p = e & 15;
    int g = c >> 2;
    float xv = x[c * HWSZ + p0 + p];
    float xn = (xv - stats_lds[g][0]) * stats_lds[g][1] * gamma[c] + beta[c];
    xnT[p][c] = __float2bfloat16(xn);
  }
  __syncthreads();
  int lane = t & 63, w = t >> 6;
  int l15 = lane & 15, g = lane >> 4;
  FragU bfr[4];
#pragma unroll
  for (int kk = 0; kk < 4; ++kk)
    bfr[kk].u = *reinterpret_cast<const uint4*>(&xnT[l15][kk * 32 + 8 * g]);
  int o0 = w * 16;
#define DO_CONV(WMAT, BIAS, BSCALE, LDSW)                                        \
  {                                                                              \
    f32x4 bi = *reinterpret_cast<const f32x4*>((BIAS) + o0 + 4 * g);             \
    f32x4 acc = bi * (BSCALE);                                                   \
    _Pragma("unroll") for (int kk = 0; kk < 4; ++kk) {                           \
      FragU a;                                                                   \
      a.u = *reinterpret_cast<const uint4*>((WMAT) +                             \
            (o0 + l15) * 128 + kk * 32 + 8 * g);                                 \
      acc = __builtin_amdgcn_mfma_f32_16x16x32_bf16(a.v, bfr[kk].v, acc, 0, 0, 0); \
    }                                                                            \
    _Pragma("unroll") for (int r = 0; r < 4; ++r) {                              \
      int o = o0 + 4 * g + r;                                                    \
      LDSW;                                                                      \
    }                                                                            \
  }
  DO_CONV(wb, bq, QSCALE2, qs_[o & 3][l15][o >> 2] = __float2bfloat16(acc[r]))
  DO_CONV(wb + 16384, bk, 1.0f, ks_[o & 3][l15][o >> 2] = __float2bfloat16(acc[r]))
  DO_CONV(wb + 32768, bv, 1.0f, vs_[o][l15] = __float2bfloat16(acc[r]))
#undef DO_CONV
  __syncthreads();
  if (t < 256) {
    int row = t >> 2, ch = t & 3;
    int h = row >> 4, p = row & 15;
    uint4 vq = *reinterpret_cast<const uint4*>(&qs_[h][p][ch * 8]);
    *reinterpret_cast<uint4*>(qt + (h * HWSZ + p0 + p) * 32 + ch * 8) = vq;
  } else {
    int tt = t - 256;
    int row = tt >> 2, ch = tt & 3;
    int h = row >> 4, p = row & 15;
    uint4 vk = *reinterpret_cast<const uint4*>(&ks_[h][p][ch * 8]);
    *reinterpret_cast<uint4*>(kt + (h * HWSZ + p0 + p) * 32 + ch * 8) = vk;
  }
  if (t < 256) {
    int o = t >> 1, half = t & 1;
    uint4 vv = *reinterpret_cast<const uint4*>(&vs_[o][half * 8]);
    *reinterpret_cast<uint4*>(vb + o * HWSZ + p0 + half * 8) = vv;
  }
}

// ---------------- K3: per-key-column sum(exp2(S2)) partials via MFMA --------
// A = K-tile (m=key), B = Q-tile (n=query) -> D = S2^T tile. 64 keys/wave.
// QSPLIT=32 -> 2048 blocks = 8/CU = full 32 waves/CU (trans latency hiding).
// colpart is KEY-MAJOR: colpart[(h*HWSZ + k)*QSPLIT + qs].
__global__ __launch_bounds__(256, 8) void colstats_kernel(
    const __hip_bfloat16* __restrict__ qt, const __hip_bfloat16* __restrict__ kt,
    float* __restrict__ colpart) {
  int h = blockIdx.y, t = threadIdx.x, qs = blockIdx.z;
  int w = t >> 6, lane = t & 63;
  int l15 = lane & 15, g = lane >> 4;
  int k0 = blockIdx.x * 256 + w * 64;
  FragU a[4];
#pragma unroll
  for (int u = 0; u < 4; ++u)
    a[u].u = *reinterpret_cast<const uint4*>(kt + (h * HWSZ + k0 + u * 16 + l15) * 32 + 8 * g);
  float l[4][4];
#pragma unroll
  for (int u = 0; u < 4; ++u)
#pragma unroll
    for (int r = 0; r < 4; ++r) l[u][r] = 0.f;
  const __hip_bfloat16* qbase =
      qt + h * HWSZ * 32 + (qs * (HWSZ / QSPLIT) + l15) * 32 + 8 * g;
  f32x4 z = {0.f, 0.f, 0.f, 0.f};
#pragma unroll 4
  for (int it = 0; it < HWSZ / QSPLIT / 16; ++it) {
    FragU b;
    b.u = *reinterpret_cast<const uint4*>(qbase + it * 512);
#pragma unroll
    for (int u = 0; u < 4; ++u) {
      f32x4 d = __builtin_amdgcn_mfma_f32_16x16x32_bf16(a[u].v, b.v, z, 0, 0, 0);
#pragma unroll
      for (int r = 0; r < 4; ++r) l[u][r] += EXP2F(d[r]);
    }
  }
#pragma unroll
  for (int off = 1; off < 16; off <<= 1)
#pragma unroll
    for (int u = 0; u < 4; ++u)
#pragma unroll
      for (int r = 0; r < 4; ++r) l[u][r] += __shfl_xor(l[u][r], off);
  if (l15 == 0) {
#pragma unroll
    for (int u = 0; u < 4; ++u)
#pragma unroll
      for (int r = 0; r < 4; ++r)
        colpart[(h * HWSZ + k0 + u * 16 + 4 * g + r) * QSPLIT + qs] = l[u][r];
  }
}

// ---------------- K4: c2 combine (coalesced) + S2+C via MFMA, P=exp2, PV ----
// 64 queries/wave (4 q-subtiles share K/V fragment loads).
__global__ __launch_bounds__(256, 2) void attn_pv_kernel(
    const __hip_bfloat16* __restrict__ qt, const __hip_bfloat16* __restrict__ kt,
    const __hip_bfloat16* __restrict__ vb, const float* __restrict__ colpart,
    __hip_bfloat16* __restrict__ aopb) {
  __shared__ __align__(16) char p_lds[4][4][2048];  // [wave][qsub][16 rows x 128B]
  __shared__ float c2_lds[HWSZ / KSPLIT];           // 512 f32
  int h = blockIdx.y, t = threadIdx.x;
  int kc0 = blockIdx.z * (HWSZ / KSPLIT);
#pragma unroll
  for (int e = t; e < HWSZ / KSPLIT; e += 256) {
    const f32x4* pp = reinterpret_cast<const f32x4*>(
        colpart + (h * HWSZ + kc0 + e) * QSPLIT);
    f32x4 s4 = pp[0];
#pragma unroll
    for (int q4 = 1; q4 < QSPLIT / 4; ++q4) s4 += pp[q4];
    float s = (s4[0] + s4[1]) + (s4[2] + s4[3]);
    c2_lds[e] = -__log2f(s);
  }
  __syncthreads();
  int w = t >> 6, lane = t & 63;
  int l15 = lane & 15, g = lane >> 4;
  int swz = l15 & 7;
  int i0 = blockIdx.x * 256 + w * 64;
  FragU bq[4];
#pragma unroll
  for (int qs = 0; qs < 4; ++qs)
    bq[qs].u = *reinterpret_cast<const uint4*>(
        qt + (h * HWSZ + i0 + qs * 16 + l15) * 32 + 8 * g);
  f32x4 acc[4][2];
#pragma unroll
  for (int qs = 0; qs < 4; ++qs)
#pragma unroll
    for (int ch = 0; ch < 2; ++ch) acc[qs][ch] = (f32x4){0.f, 0.f, 0.f, 0.f};
  __hip_bfloat16* ao = aopb + blockIdx.z * (128 * HWSZ);
  for (int k0 = kc0; k0 < kc0 + HWSZ / KSPLIT; k0 += 64) {
    FragU a[4];
    f32x4 c2[4];
#pragma unroll
    for (int kt4 = 0; kt4 < 4; ++kt4) {
      a[kt4].u = *reinterpret_cast<const uint4*>(
          kt + (h * HWSZ + k0 + kt4 * 16 + l15) * 32 + 8 * g);
      c2[kt4] = *reinterpret_cast<const f32x4*>(c2_lds + (k0 - kc0) + kt4 * 16 + 4 * g);
    }
    FragU bvf[2][2];  // [ks][ch]
#pragma unroll
    for (int ks = 0; ks < 2; ++ks)
#pragma unroll
      for (int ch = 0; ch < 2; ++ch)
        bvf[ks][ch].u = *reinterpret_cast<const uint4*>(
            vb + ((l15 + 16 * ch) * 4 + h) * HWSZ + k0 + ks * 32 + 8 * g);
#pragma unroll
    for (int qs = 0; qs < 4; ++qs) {
      f32x4 st[4];
#pragma unroll
      for (int kt4 = 0; kt4 < 4; ++kt4)
        st[kt4] = __builtin_amdgcn_mfma_f32_16x16x32_bf16(a[kt4].v, bq[qs].v,
                                                          c2[kt4], 0, 0, 0);
      char* pw = p_lds[w][qs];
#pragma unroll
      for (int kt4 = 0; kt4 < 4; ++kt4) {
        uint2 pk;
        pk.x = cvt_pk_bf16(EXP2F(st[kt4][0]), EXP2F(st[kt4][1]));
        pk.y = cvt_pk_bf16(EXP2F(st[kt4][2]), EXP2F(st[kt4][3]));
        int c8 = kt4 * 4 + g;  // 8-byte chunk index in 128B row
        int byte_w = l15 * 128 + ((((c8 >> 1) ^ swz)) << 4) + ((c8 & 1) << 3);
        *reinterpret_cast<uint2*>(pw + byte_w) = pk;
      }
#pragma unroll
      for (int ks = 0; ks < 2; ++ks) {
        FragU ap;
        int byte_r = l15 * 128 + (((ks * 4 + g) ^ swz) << 4);
        ap.u = *reinterpret_cast<const uint4*>(pw + byte_r);
#pragma unroll
        for (int ch = 0; ch < 2; ++ch)
          acc[qs][ch] = __builtin_amdgcn_mfma_f32_16x16x32_bf16(
              ap.v, bvf[ks][ch].v, acc[qs][ch], 0, 0, 0);
      }
    }
  }
#pragma unroll
  for (int qs = 0; qs < 4; ++qs)
#pragma unroll
    for (int ch = 0; ch < 2; ++ch) {
      uint2 pk;
      pk.x = cvt_pk_bf16(acc[qs][ch][0], acc[qs][ch][1]);
      pk.y = cvt_pk_bf16(acc[qs][ch][2], acc[qs][ch][3]);
      *reinterpret_cast<uint2*>(
          ao + ((l15 + 16 * ch) * 4 + h) * HWSZ + i0 + qs * 16 + 4 * g) = pk;
    }
}

// ---------------- K5: reduce bf16 split-k partials + proj via MFMA ----------
__global__ __launch_bounds__(512) void proj_mfma_kernel(
    const __hip_bfloat16* __restrict__ aopb, const __hip_bfloat16* __restrict__ wpb,
    const float* __restrict__ bp, const float* __restrict__ x,
    float* __restrict__ out) {
  __shared__ __align__(16) __hip_bfloat16 aoT[16][136];
  __shared__ __align__(16) float obuf[128][20];
  int t = threadIdx.x;
  int p0 = blockIdx.x * 16;
  if (t < 256) {
    int c = t >> 1, half = t & 1;
    float s[8];
#pragma unroll
    for (int j = 0; j < 8; ++j) s[j] = 0.f;
#pragma unroll
    for (int z = 0; z < KSPLIT; ++z) {
      FragU u;
      u.u = *reinterpret_cast<const uint4*>(aopb + z * (128 * HWSZ) + c * HWSZ + p0 + half * 8);
#pragma unroll
      for (int j = 0; j < 8; ++j) s[j] += (float)u.v[j];
    }
#pragma unroll
    for (int j = 0; j < 8; ++j) aoT[half * 8 + j][c] = __float2bfloat16(s[j]);
  }
  __syncthreads();
  int lane = t & 63, w = t >> 6;
  int l15 = lane & 15, g = lane >> 4;
  FragU bfr[4];
#pragma unroll
  for (int kk = 0; kk < 4; ++kk)
    bfr[kk].u = *reinterpret_cast<const uint4*>(&aoT[l15][kk * 32 + 8 * g]);
  int o0 = w * 16;
  f32x4 acc = *reinterpret_cast<const f32x4*>(bp + o0 + 4 * g);
#pragma unroll
  for (int kk = 0; kk < 4; ++kk) {
    FragU a;
    a.u = *reinterpret_cast<const uint4*>(wpb + (o0 + l15) * 128 + kk * 32 + 8 * g);
    acc = __builtin_amdgcn_mfma_f32_16x16x32_bf16(a.v, bfr[kk].v, acc, 0, 0, 0);
  }
#pragma unroll
  for (int r = 0; r < 4; ++r) obuf[o0 + 4 * g + r][l15] = acc[r];
  __syncthreads();
  int row = t >> 2, ch = t & 3;
  float4 o4 = *reinterpret_cast<const float4*>(&obuf[row][ch * 4]);
  float4 xv = *reinterpret_cast<const float4*>(x + row * HWSZ + p0 + ch * 4);
  float4 rr = {o4.x + xv.x, o4.y + xv.y, o4.z + xv.z, o4.w + xv.w};
  *reinterpret_cast<float4*>(out + row * HWSZ + p0 + ch * 4) = rr;
}

extern "C" void kernel_launch(void* const* d_in, const int* in_sizes, int n_in,
                              void* d_out, int out_size, void* d_ws, size_t ws_size,
                              hipStream_t stream) {
  const float* x = (const float*)d_in[0];
  const float* gamma = (const float*)d_in[1];
  const float* beta = (const float*)d_in[2];
  const float* wq = (const float*)d_in[3];
  const float* bq = (const float*)d_in[4];
  const float* wk = (const float*)d_in[5];
  const float* bk = (const float*)d_in[6];
  const float* wv = (const float*)d_in[7];
  const float* bv = (const float*)d_in[8];
  const float* wp = (const float*)d_in[9];
  const float* bp = (const float*)d_in[10];
  float* out = (float*)d_out;

  char* ws = (char*)d_ws;
  __hip_bfloat16* qt = (__hip_bfloat16*)(ws);                    // 1 MB
  __hip_bfloat16* kt = (__hip_bfloat16*)(ws + (1 << 20));        // 1 MB
  __hip_bfloat16* vb = (__hip_bfloat16*)(ws + (2 << 20));        // 1 MB
  __hip_bfloat16* aopb = (__hip_bfloat16*)(ws + (3 << 20));      // KSPLIT MB
  char* tail = ws + ((3 + KSPLIT) << 20);
  float* colpart = (float*)(tail);                               // 2 MB (key-major)
  __hip_bfloat16* wb = (__hip_bfloat16*)(tail + (2 << 20));      // 128 KB (4 mats)
  float* gnpart = (float*)(tail + (2 << 20) + (128 << 10));      // 1 KB

  prep_kernel<<<192, 256, 0, stream>>>(wq, wk, wv, wp, x, wb, gnpart);
  qkv_mfma_kernel<<<256, 512, 0, stream>>>(x, gnpart, gamma, beta, wb, bq, bk, bv,
                                           qt, kt, vb);
  colstats_kernel<<<dim3(16, 4, QSPLIT), 256, 0, stream>>>(qt, kt, colpart);
  attn_pv_kernel<<<dim3(16, 4, KSPLIT), 256, 0, stream>>>(qt, kt, vb, colpart, aopb);
  proj_mfma_kernel<<<256, 512, 0, stream>>>(aopb, wb + 49152, bp, x, out);
}

// Round 14
// 51.352 us; speedup vs baseline: 4.7111x; 1.0930x over previous
//
#include <hip/hip_runtime.h>
#include <hip/hip_bf16.h>

// MultiHeadAttnBlock: B=1, C=128, HEADS=4 (cph=32), GROUPS=32, H=W=64 (HW=4096)
// softmax over QUERY axis => per-key-column normalizer; log2-domain softmax
// (qt & wq pre-scaled by 128^-0.5*log2e); normalizer c2=-log2(colsum) folded
// into the QK^T MFMA C-operand. 5 kernels; the dep chain
// stats -> qkv -> colsum -> pv -> proj is irreducibly 5 launches
// (grid.sync ~55us on MI355X, R7; per-boundary gap ~6.5us, R12 diag).
// R14 = exact revert to R11 (verified 51.7us best). R13's colstats
// QSPLIT=32 + key-major colpart regressed (scattered epilogue stores,
// 2x combine traffic, tiny per-block loops); colstats at QSPLIT=16 is at
// its exp2-issue floor (VALUBusy 71%, R12).

#define HWSZ 4096
#define QSCALE2 0.12752649759422368f  // 128^-0.5 * log2(e)
#define QSPLIT 16                     // colstats query-axis split
#define KSPLIT 8                      // attn_pv key-axis split
#define EPS 1e-6f

typedef __bf16 bf16x8 __attribute__((ext_vector_type(8)));
typedef float f32x4 __attribute__((ext_vector_type(4)));

union FragU { uint4 u; bf16x8 v; };

#if __has_builtin(__builtin_amdgcn_exp2f)
#define EXP2F(x) __builtin_amdgcn_exp2f(x)
#else
#define EXP2F(x) exp2f(x)
#endif

// pack two f32 -> two bf16 (round-half via +0x8000, then v_perm byte select)
__device__ __forceinline__ unsigned int pack_bf16(float lo, float hi) {
  unsigned int ul, uh;
  __builtin_memcpy(&ul, &lo, 4);
  __builtin_memcpy(&uh, &hi, 4);
  return __builtin_amdgcn_perm(uh + 0x8000u, ul + 0x8000u, 0x07060302u);
}

// single-instruction packed f32->bf16 (RNE), gfx950. D[15:0]=bf16(lo), D[31:16]=bf16(hi)
__device__ __forceinline__ unsigned int cvt_pk_bf16(float lo, float hi) {
  unsigned int r;
  asm("v_cvt_pk_bf16_f32 %0, %1, %2" : "=v"(r) : "v"(lo), "v"(hi));
  return r;
}

// ---------------- K1: prep — weight cvt to bf16 + per-channel GN partials ---
__global__ __launch_bounds__(256) void prep_kernel(
    const float* __restrict__ wq, const float* __restrict__ wk,
    const float* __restrict__ wv, const float* __restrict__ wp,
    const float* __restrict__ x, __hip_bfloat16* __restrict__ wb,
    float* __restrict__ gnpart) {
  int b = blockIdx.x, t = threadIdx.x;
  if (b < 64) {
    int m = b >> 4, chunk = b & 15;
    const float* src = (m == 0) ? wq : (m == 1) ? wk : (m == 2) ? wv : wp;
    float sc = (m == 0) ? QSCALE2 : 1.0f;
    int idx = chunk * 1024 + t * 4;
    float4 v = *reinterpret_cast<const float4*>(src + idx);
    uint2 st;
    st.x = pack_bf16(v.x * sc, v.y * sc);
    st.y = pack_bf16(v.z * sc, v.w * sc);
    *reinterpret_cast<uint2*>(wb + m * 16384 + idx) = st;
  } else {
    int ch = b - 64;
    const float4* x4 = reinterpret_cast<const float4*>(x + ch * HWSZ);
    float s = 0.f, ss = 0.f;
    for (int e = t; e < 1024; e += 256) {
      float4 v = x4[e];
      s += v.x + v.y + v.z + v.w;
      ss += v.x * v.x + v.y * v.y + v.z * v.z + v.w * v.w;
    }
    for (int off = 32; off; off >>= 1) {
      s += __shfl_down(s, off);
      ss += __shfl_down(ss, off);
    }
    __shared__ float rs[4], rss[4];
    int wid = t >> 6;
    if ((t & 63) == 0) { rs[wid] = s; rss[wid] = ss; }
    __syncthreads();
    if (t == 0) {
      gnpart[ch] = rs[0] + rs[1] + rs[2] + rs[3];
      gnpart[128 + ch] = rss[0] + rss[1] + rss[2] + rss[3];
    }
  }
}

// ---------------- K2: GN-apply + QKV as MFMA GEMM (512 thr, coalesced epi) --
// mfma_f32_16x16x32_bf16: A[m=l&15][k=8*(l>>4)+j], B[k][n=l&15],
//                         D[row=(l>>4)*4+reg][col=l&15]
__global__ __launch_bounds__(512) void qkv_mfma_kernel(
    const float* __restrict__ x, const float* __restrict__ gnpart,
    const float* __restrict__ gamma, const float* __restrict__ beta,
    const __hip_bfloat16* __restrict__ wb, const float* __restrict__ bq,
    const float* __restrict__ bk, const float* __restrict__ bv,
    __hip_bfloat16* __restrict__ qt, __hip_bfloat16* __restrict__ kt,
    __hip_bfloat16* __restrict__ vb) {
  __shared__ float stats_lds[32][2];
  __shared__ __align__(16) __hip_bfloat16 xnT[16][136];
  __shared__ __align__(16) __hip_bfloat16 qs_[4][16][40];
  __shared__ __align__(16) __hip_bfloat16 ks_[4][16][40];
  __shared__ __align__(16) __hip_bfloat16 vs_[128][24];
  int t = threadIdx.x;
  int p0 = blockIdx.x * 16;
  if (t < 32) {
    float s = 0.f, ss = 0.f;
#pragma unroll
    for (int q = 0; q < 4; ++q) {
      s += gnpart[t * 4 + q];
      ss += gnpart[128 + t * 4 + q];
    }
    float mu = s * (1.f / 16384.f);
    float var = ss * (1.f / 16384.f) - mu * mu;
    stats_lds[t][0] = mu;
    stats_lds[t][1] = rsqrtf(var + EPS);
  }
  __syncthreads();
#pragma unroll
  for (int e = t; e < 2048; e += 512) {
    int c = e >> 4, p = e & 15;
    int g = c >> 2;
    float xv = x[c * HWSZ + p0 + p];
    float xn = (xv - stats_lds[g][0]) * stats_lds[g][1] * gamma[c] + beta[c];
    xnT[p][c] = __float2bfloat16(xn);
  }
  __syncthreads();
  int lane = t & 63, w = t >> 6;
  int l15 = lane & 15, g = lane >> 4;
  FragU bfr[4];
#pragma unroll
  for (int kk = 0; kk < 4; ++kk)
    bfr[kk].u = *reinterpret_cast<const uint4*>(&xnT[l15][kk * 32 + 8 * g]);
  int o0 = w * 16;
#define DO_CONV(WMAT, BIAS, BSCALE, LDSW)                                        \
  {                                                                              \
    f32x4 bi = *reinterpret_cast<const f32x4*>((BIAS) + o0 + 4 * g);             \
    f32x4 acc = bi * (BSCALE);                                                   \
    _Pragma("unroll") for (int kk = 0; kk < 4; ++kk) {                           \
      FragU a;                                                                   \
      a.u = *reinterpret_cast<const uint4*>((WMAT) +                             \
            (o0 + l15) * 128 + kk * 32 + 8 * g);                                 \
      acc = __builtin_amdgcn_mfma_f32_16x16x32_bf16(a.v, bfr[kk].v, acc, 0, 0, 0); \
    }                                                                            \
    _Pragma("unroll") for (int r = 0; r < 4; ++r) {                              \
      int o = o0 + 4 * g + r;                                                    \
      LDSW;                                                                      \
    }                                                                            \
  }
  DO_CONV(wb, bq, QSCALE2, qs_[o & 3][l15][o >> 2] = __float2bfloat16(acc[r]))
  DO_CONV(wb + 16384, bk, 1.0f, ks_[o & 3][l15][o >> 2] = __float2bfloat16(acc[r]))
  DO_CONV(wb + 32768, bv, 1.0f, vs_[o][l15] = __float2bfloat16(acc[r]))
#undef DO_CONV
  __syncthreads();
  if (t < 256) {
    int row = t >> 2, ch = t & 3;
    int h = row >> 4, p = row & 15;
    uint4 vq = *reinterpret_cast<const uint4*>(&qs_[h][p][ch * 8]);
    *reinterpret_cast<uint4*>(qt + (h * HWSZ + p0 + p) * 32 + ch * 8) = vq;
  } else {
    int tt = t - 256;
    int row = tt >> 2, ch = tt & 3;
    int h = row >> 4, p = row & 15;
    uint4 vk = *reinterpret_cast<const uint4*>(&ks_[h][p][ch * 8]);
    *reinterpret_cast<uint4*>(kt + (h * HWSZ + p0 + p) * 32 + ch * 8) = vk;
  }
  if (t < 256) {
    int o = t >> 1, half = t & 1;
    uint4 vv = *reinterpret_cast<const uint4*>(&vs_[o][half * 8]);
    *reinterpret_cast<uint4*>(vb + o * HWSZ + p0 + half * 8) = vv;
  }
}

// ---------------- K3: per-key-column sum(exp2(S2)) partials via MFMA --------
// A = K-tile (m=key), B = Q-tile (n=query) -> D = S2^T tile. 64 keys/wave.
__global__ __launch_bounds__(256, 4) void colstats_kernel(
    const __hip_bfloat16* __restrict__ qt, const __hip_bfloat16* __restrict__ kt,
    float* __restrict__ colpart) {
  int h = blockIdx.y, t = threadIdx.x, qs = blockIdx.z;
  int w = t >> 6, lane = t & 63;
  int l15 = lane & 15, g = lane >> 4;
  int k0 = blockIdx.x * 256 + w * 64;
  FragU a[4];
#pragma unroll
  for (int u = 0; u < 4; ++u)
    a[u].u = *reinterpret_cast<const uint4*>(kt + (h * HWSZ + k0 + u * 16 + l15) * 32 + 8 * g);
  float l[4][4];
#pragma unroll
  for (int u = 0; u < 4; ++u)
#pragma unroll
    for (int r = 0; r < 4; ++r) l[u][r] = 0.f;
  const __hip_bfloat16* qbase =
      qt + h * HWSZ * 32 + (qs * (HWSZ / QSPLIT) + l15) * 32 + 8 * g;
  f32x4 z = {0.f, 0.f, 0.f, 0.f};
#pragma unroll 2
  for (int it = 0; it < HWSZ / QSPLIT / 16; ++it) {
    FragU b;
    b.u = *reinterpret_cast<const uint4*>(qbase + it * 512);
#pragma unroll
    for (int u = 0; u < 4; ++u) {
      f32x4 d = __builtin_amdgcn_mfma_f32_16x16x32_bf16(a[u].v, b.v, z, 0, 0, 0);
#pragma unroll
      for (int r = 0; r < 4; ++r) l[u][r] += EXP2F(d[r]);
    }
  }
#pragma unroll
  for (int off = 1; off < 16; off <<= 1)
#pragma unroll
    for (int u = 0; u < 4; ++u)
#pragma unroll
      for (int r = 0; r < 4; ++r) l[u][r] += __shfl_xor(l[u][r], off);
  if (l15 == 0) {
#pragma unroll
    for (int u = 0; u < 4; ++u)
#pragma unroll
      for (int r = 0; r < 4; ++r)
        colpart[(qs * 4 + h) * HWSZ + k0 + u * 16 + 4 * g + r] = l[u][r];
  }
}

// ---------------- K4: c2 combine + S2+C via MFMA, P=exp2, PV ----------------
// 64 queries/wave (4 q-subtiles share K/V fragment loads -> half L2 traffic).
// Block: 256 queries x 1 head x 512 keys. c2 prologue from colpart.
__global__ __launch_bounds__(256, 2) void attn_pv_kernel(
    const __hip_bfloat16* __restrict__ qt, const __hip_bfloat16* __restrict__ kt,
    const __hip_bfloat16* __restrict__ vb, const float* __restrict__ colpart,
    __hip_bfloat16* __restrict__ aopb) {
  __shared__ __align__(16) char p_lds[4][4][2048];  // [wave][qsub][16 rows x 128B]
  __shared__ float c2_lds[HWSZ / KSPLIT];           // 512 f32
  int h = blockIdx.y, t = threadIdx.x;
  int kc0 = blockIdx.z * (HWSZ / KSPLIT);
#pragma unroll
  for (int e = t; e < HWSZ / KSPLIT; e += 256) {
    float s = 0.f;
#pragma unroll
    for (int qs = 0; qs < QSPLIT; ++qs) s += colpart[(qs * 4 + h) * HWSZ + kc0 + e];
    c2_lds[e] = -__log2f(s);
  }
  __syncthreads();
  int w = t >> 6, lane = t & 63;
  int l15 = lane & 15, g = lane >> 4;
  int swz = l15 & 7;
  int i0 = blockIdx.x * 256 + w * 64;
  FragU bq[4];
#pragma unroll
  for (int qs = 0; qs < 4; ++qs)
    bq[qs].u = *reinterpret_cast<const uint4*>(
        qt + (h * HWSZ + i0 + qs * 16 + l15) * 32 + 8 * g);
  f32x4 acc[4][2];
#pragma unroll
  for (int qs = 0; qs < 4; ++qs)
#pragma unroll
    for (int ch = 0; ch < 2; ++ch) acc[qs][ch] = (f32x4){0.f, 0.f, 0.f, 0.f};
  __hip_bfloat16* ao = aopb + blockIdx.z * (128 * HWSZ);
  for (int k0 = kc0; k0 < kc0 + HWSZ / KSPLIT; k0 += 64) {
    FragU a[4];
    f32x4 c2[4];
#pragma unroll
    for (int kt4 = 0; kt4 < 4; ++kt4) {
      a[kt4].u = *reinterpret_cast<const uint4*>(
          kt + (h * HWSZ + k0 + kt4 * 16 + l15) * 32 + 8 * g);
      c2[kt4] = *reinterpret_cast<const f32x4*>(c2_lds + (k0 - kc0) + kt4 * 16 + 4 * g);
    }
    FragU bvf[2][2];  // [ks][ch]
#pragma unroll
    for (int ks = 0; ks < 2; ++ks)
#pragma unroll
      for (int ch = 0; ch < 2; ++ch)
        bvf[ks][ch].u = *reinterpret_cast<const uint4*>(
            vb + ((l15 + 16 * ch) * 4 + h) * HWSZ + k0 + ks * 32 + 8 * g);
#pragma unroll
    for (int qs = 0; qs < 4; ++qs) {
      f32x4 st[4];
#pragma unroll
      for (int kt4 = 0; kt4 < 4; ++kt4)
        st[kt4] = __builtin_amdgcn_mfma_f32_16x16x32_bf16(a[kt4].v, bq[qs].v,
                                                          c2[kt4], 0, 0, 0);
      char* pw = p_lds[w][qs];
#pragma unroll
      for (int kt4 = 0; kt4 < 4; ++kt4) {
        uint2 pk;
        pk.x = cvt_pk_bf16(EXP2F(st[kt4][0]), EXP2F(st[kt4][1]));
        pk.y = cvt_pk_bf16(EXP2F(st[kt4][2]), EXP2F(st[kt4][3]));
        int c8 = kt4 * 4 + g;  // 8-byte chunk index in 128B row
        int byte_w = l15 * 128 + ((((c8 >> 1) ^ swz)) << 4) + ((c8 & 1) << 3);
        *reinterpret_cast<uint2*>(pw + byte_w) = pk;
      }
#pragma unroll
      for (int ks = 0; ks < 2; ++ks) {
        FragU ap;
        int byte_r = l15 * 128 + (((ks * 4 + g) ^ swz) << 4);
        ap.u = *reinterpret_cast<const uint4*>(pw + byte_r);
#pragma unroll
        for (int ch = 0; ch < 2; ++ch)
          acc[qs][ch] = __builtin_amdgcn_mfma_f32_16x16x32_bf16(
              ap.v, bvf[ks][ch].v, acc[qs][ch], 0, 0, 0);
      }
    }
  }
#pragma unroll
  for (int qs = 0; qs < 4; ++qs)
#pragma unroll
    for (int ch = 0; ch < 2; ++ch) {
      uint2 pk;
      pk.x = cvt_pk_bf16(acc[qs][ch][0], acc[qs][ch][1]);
      pk.y = cvt_pk_bf16(acc[qs][ch][2], acc[qs][ch][3]);
      *reinterpret_cast<uint2*>(
          ao + ((l15 + 16 * ch) * 4 + h) * HWSZ + i0 + qs * 16 + 4 * g) = pk;
    }
}

// ---------------- K5: reduce bf16 split-k partials + proj via MFMA ----------
__global__ __launch_bounds__(512) void proj_mfma_kernel(
    const __hip_bfloat16* __restrict__ aopb, const __hip_bfloat16* __restrict__ wpb,
    const float* __restrict__ bp, const float* __restrict__ x,
    float* __restrict__ out) {
  __shared__ __align__(16) __hip_bfloat16 aoT[16][136];
  __shared__ __align__(16) float obuf[128][20];
  int t = threadIdx.x;
  int p0 = blockIdx.x * 16;
  if (t < 256) {
    int c = t >> 1, half = t & 1;
    float s[8];
#pragma unroll
    for (int j = 0; j < 8; ++j) s[j] = 0.f;
#pragma unroll
    for (int z = 0; z < KSPLIT; ++z) {
      FragU u;
      u.u = *reinterpret_cast<const uint4*>(aopb + z * (128 * HWSZ) + c * HWSZ + p0 + half * 8);
#pragma unroll
      for (int j = 0; j < 8; ++j) s[j] += (float)u.v[j];
    }
#pragma unroll
    for (int j = 0; j < 8; ++j) aoT[half * 8 + j][c] = __float2bfloat16(s[j]);
  }
  __syncthreads();
  int lane = t & 63, w = t >> 6;
  int l15 = lane & 15, g = lane >> 4;
  FragU bfr[4];
#pragma unroll
  for (int kk = 0; kk < 4; ++kk)
    bfr[kk].u = *reinterpret_cast<const uint4*>(&aoT[l15][kk * 32 + 8 * g]);
  int o0 = w * 16;
  f32x4 acc = *reinterpret_cast<const f32x4*>(bp + o0 + 4 * g);
#pragma unroll
  for (int kk = 0; kk < 4; ++kk) {
    FragU a;
    a.u = *reinterpret_cast<const uint4*>(wpb + (o0 + l15) * 128 + kk * 32 + 8 * g);
    acc = __builtin_amdgcn_mfma_f32_16x16x32_bf16(a.v, bfr[kk].v, acc, 0, 0, 0);
  }
#pragma unroll
  for (int r = 0; r < 4; ++r) obuf[o0 + 4 * g + r][l15] = acc[r];
  __syncthreads();
  int row = t >> 2, ch = t & 3;
  float4 o4 = *reinterpret_cast<const float4*>(&obuf[row][ch * 4]);
  float4 xv = *reinterpret_cast<const float4*>(x + row * HWSZ + p0 + ch * 4);
  float4 rr = {o4.x + xv.x, o4.y + xv.y, o4.z + xv.z, o4.w + xv.w};
  *reinterpret_cast<float4*>(out + row * HWSZ + p0 + ch * 4) = rr;
}

extern "C" void kernel_launch(void* const* d_in, const int* in_sizes, int n_in,
                              void* d_out, int out_size, void* d_ws, size_t ws_size,
                              hipStream_t stream) {
  const float* x = (const float*)d_in[0];
  const float* gamma = (const float*)d_in[1];
  const float* beta = (const float*)d_in[2];
  const float* wq = (const float*)d_in[3];
  const float* bq = (const float*)d_in[4];
  const float* wk = (const float*)d_in[5];
  const float* bk = (const float*)d_in[6];
  const float* wv = (const float*)d_in[7];
  const float* bv = (const float*)d_in[8];
  const float* wp = (const float*)d_in[9];
  const float* bp = (const float*)d_in[10];
  float* out = (float*)d_out;

  char* ws = (char*)d_ws;
  __hip_bfloat16* qt = (__hip_bfloat16*)(ws);                    // 1 MB
  __hip_bfloat16* kt = (__hip_bfloat16*)(ws + (1 << 20));        // 1 MB
  __hip_bfloat16* vb = (__hip_bfloat16*)(ws + (2 << 20));        // 1 MB
  __hip_bfloat16* aopb = (__hip_bfloat16*)(ws + (3 << 20));      // KSPLIT MB
  char* tail = ws + ((3 + KSPLIT) << 20);
  float* colpart = (float*)(tail);                               // 1 MB
  __hip_bfloat16* wb = (__hip_bfloat16*)(tail + (1 << 20));      // 128 KB (4 mats)
  float* gnpart = (float*)(tail + (1 << 20) + (128 << 10));      // 1 KB

  prep_kernel<<<192, 256, 0, stream>>>(wq, wk, wv, wp, x, wb, gnpart);
  qkv_mfma_kernel<<<256, 512, 0, stream>>>(x, gnpart, gamma, beta, wb, bq, bk, bv,
                                           qt, kt, vb);
  colstats_kernel<<<dim3(16, 4, QSPLIT), 256, 0, stream>>>(qt, kt, colpart);
  attn_pv_kernel<<<dim3(16, 4, KSPLIT), 256, 0, stream>>>(qt, kt, vb, colpart, aopb);
  proj_mfma_kernel<<<256, 512, 0, stream>>>(aopb, wb + 49152, bp, x, out);
}